// Round 1
// baseline (686.734 us; speedup 1.0000x reference)
//
#include <hip/hip_runtime.h>
#include <hip/hip_bf16.h>
#include <math.h>

// ---------------------------------------------------------------------------
// MoE block: y = sum_topk2 w_e * FFN_e(x)  +  FFN_shared(x)
// T=4096 tokens, D=1024, H=4096, E=8, K=2.  All inputs fp32; compute in bf16
// MFMA (threshold sanctions bf16: floor_eps_k=8 path).
// Pipeline: gate -> scan(pad-to-128 slots) -> build bf16 X -> transpose+cvt
// weights -> 4x gemm_bt (128x128 tile, mfma 16x16x32 bf16, global_load_lds
// w/ pre-swizzled source) -> combine.
// ---------------------------------------------------------------------------

typedef unsigned short ushort_t;
typedef __attribute__((ext_vector_type(8))) __bf16 bf16x8;
typedef __attribute__((ext_vector_type(4))) float f32x4;

#define T_TOK 4096
#define DDIM  1024
#define HDIM  4096
#define NEXP  8
#define SLOT_MAX 9216   // 8192 + 8*128 pad headroom

// workspace layout (bytes)
#define OFF_TIDX  0u            // int[8192]
#define OFF_TW    32768u        // float[8192]
#define OFF_OFFS  65536u        // int[16]
#define OFF_SLOT  65792u        // int[8192]
#define OFF_TOK   98560u        // int[9216]
#define OFF_XG    262144u                         // bf16 [9216][1024] = 18,874,368
#define OFF_XB    (OFF_XG + 18874368u)            // bf16 [4096][1024] =  8,388,608
#define OFF_W     (OFF_XB + 8388608u)             // 67,108,864 (W1t / W2t / SW1t+SW2t)
#define OFF_SW2   (OFF_W + 33554432u)             // SW2t inside W region
#define OFF_H     (OFF_W + 67108864u)             // bf16 [9216][4096] = 75,497,472 (Hexp / Hsh)
#define OFF_OUTS  (OFF_H + 75497472u)             // bf16 [9216][1024] = 18,874,368

__device__ __forceinline__ ushort_t f2b(float f) {
    __hip_bfloat16 h = __float2bfloat16(f);
    return *reinterpret_cast<ushort_t*>(&h);
}
__device__ __forceinline__ float b2f(ushort_t u) {
    __hip_bfloat16 h;
    *reinterpret_cast<ushort_t*>(&h) = u;
    return __bfloat162float(h);
}
__device__ __forceinline__ float gelu_exact(float v) {
    return 0.5f * v * (1.0f + erff(v * 0.70710678118654752f));
}

// -------------------------------- gate -------------------------------------
__global__ void gate_kernel(const float* __restrict__ x, const float* __restrict__ gw,
                            int* __restrict__ tidx, float* __restrict__ tw) {
    int t = blockIdx.x;
    int l = threadIdx.x;
    float acc[NEXP];
#pragma unroll
    for (int e = 0; e < NEXP; ++e) acc[e] = 0.f;
    for (int i = 0; i < DDIM / 64; ++i) {
        float xi = x[(size_t)t * DDIM + i * 64 + l];
#pragma unroll
        for (int e = 0; e < NEXP; ++e)
            acc[e] += xi * gw[e * DDIM + i * 64 + l];
    }
#pragma unroll
    for (int e = 0; e < NEXP; ++e)
        for (int off = 32; off; off >>= 1) acc[e] += __shfl_xor(acc[e], off);
    if (l == 0) {
        float m = acc[0];
#pragma unroll
        for (int e = 1; e < NEXP; ++e) m = fmaxf(m, acc[e]);
        float ex[NEXP], Z = 0.f;
#pragma unroll
        for (int e = 0; e < NEXP; ++e) { ex[e] = __expf(acc[e] - m); Z += ex[e]; }
        int b0 = 0;
#pragma unroll
        for (int e = 1; e < NEXP; ++e) if (ex[e] > ex[b0]) b0 = e;
        int b1 = (b0 == 0) ? 1 : 0;
#pragma unroll
        for (int e = 0; e < NEXP; ++e) if (e != b0 && ex[e] > ex[b1]) b1 = e;
        float inv = 1.0f / Z;
        tidx[2 * t] = b0; tidx[2 * t + 1] = b1;
        tw[2 * t] = ex[b0] * inv; tw[2 * t + 1] = ex[b1] * inv;
    }
}

// -------------------------------- scan -------------------------------------
// single wave: counts -> padded offsets -> deterministic slot assignment
__global__ void scan_kernel(const int* __restrict__ tidx, int* __restrict__ offs,
                            int* __restrict__ slot_of, int* __restrict__ tok_of) {
    int lane = threadIdx.x;
    int cnt[NEXP];
#pragma unroll
    for (int e = 0; e < NEXP; ++e) cnt[e] = 0;
    for (int base = 0; base < 2 * T_TOK; base += 64) {
        int v = tidx[base + lane];
#pragma unroll
        for (int e = 0; e < NEXP; ++e)
            cnt[e] += __popcll(__ballot(v == e));
    }
    int off[NEXP + 1];
    off[0] = 0;
#pragma unroll
    for (int e = 0; e < NEXP; ++e) off[e + 1] = off[e] + ((cnt[e] + 127) & ~127);
    if (lane == 0) {
#pragma unroll
        for (int e = 0; e <= NEXP; ++e) offs[e] = off[e];
    }
    int run[NEXP];
#pragma unroll
    for (int e = 0; e < NEXP; ++e) run[e] = off[e];
    unsigned long long mylow = (lane == 0) ? 0ull : ((~0ull) >> (64 - lane));
    for (int base = 0; base < 2 * T_TOK; base += 64) {
        int v = tidx[base + lane];
#pragma unroll
        for (int e = 0; e < NEXP; ++e) {
            unsigned long long m = __ballot(v == e);
            if (v == e) {
                int s = run[e] + __popcll(m & mylow);
                slot_of[base + lane] = s;
                tok_of[s] = (base + lane) >> 1;
            }
            run[e] += __popcll(m);
        }
    }
#pragma unroll
    for (int e = 0; e < NEXP; ++e)
        for (int s = run[e] + lane; s < off[e + 1]; s += 64) tok_of[s] = -1;
}

// ------------------------------- build X -----------------------------------
__global__ void build_x(const float* __restrict__ x, const int* __restrict__ tok_of,
                        const int* __restrict__ offs, ushort_t* __restrict__ Xg,
                        ushort_t* __restrict__ Xb) {
    int b = blockIdx.x;
    int k = threadIdx.x * 4;
    if (b < SLOT_MAX) {
        if (b >= offs[NEXP]) return;
        int t = tok_of[b];
        float4 v = make_float4(0.f, 0.f, 0.f, 0.f);
        if (t >= 0) v = *(const float4*)(x + (size_t)t * DDIM + k);
        ushort_t* p = Xg + (size_t)b * DDIM + k;
        p[0] = f2b(v.x); p[1] = f2b(v.y); p[2] = f2b(v.z); p[3] = f2b(v.w);
    } else {
        int row = b - SLOT_MAX;
        float4 v = *(const float4*)(x + (size_t)row * DDIM + k);
        ushort_t* p = Xb + (size_t)row * DDIM + k;
        p[0] = f2b(v.x); p[1] = f2b(v.y); p[2] = f2b(v.z); p[3] = f2b(v.w);
    }
}

// --------------------------- transpose + cvt -------------------------------
// in [K][N] fp32 -> out [N][K] bf16 ; grid (K/64, N/64, batch)
__global__ void transpose_cvt(const float* __restrict__ in, ushort_t* __restrict__ out,
                              int K, int N) {
    __shared__ float t[64][65];
    size_t zoff = (size_t)blockIdx.z * K * N;
    in += zoff; out += zoff;
    int k0 = blockIdx.x * 64, n0 = blockIdx.y * 64;
    int c = threadIdx.x & 63, r4 = threadIdx.x >> 6;
#pragma unroll
    for (int i = 0; i < 16; ++i) {
        int r = r4 + i * 4;
        t[r][c] = in[(size_t)(k0 + r) * N + n0 + c];
    }
    __syncthreads();
#pragma unroll
    for (int i = 0; i < 16; ++i) {
        int r = r4 + i * 4;
        out[(size_t)(n0 + r) * K + k0 + c] = f2b(t[c][r]);
    }
}

// ------------------------------ GEMM (bt) ----------------------------------
// C[M,N] = act(A[M,K] @ Bt[N,K]^T + bias). 128x128 tile, BK=64, 4 waves,
// mfma_f32_16x16x32_bf16. LDS XOR-swizzled; source chunks pre-swizzled so
// global_load_lds linear writes land swizzled (rule #21).
template <bool EXPERT, bool ACT_GELU, bool OUT_BF16>
__global__ __launch_bounds__(256) void gemm_bt(
    const ushort_t* __restrict__ A, const ushort_t* __restrict__ BtBase,
    const float* __restrict__ biasBase, void* __restrict__ Cout,
    const int* __restrict__ offs, int N, int K) {
    int m0 = blockIdx.x * 128, n0 = blockIdx.y * 128;
    const ushort_t* Bt = BtBase;
    const float* bias = biasBase;
    if (EXPERT) {
        int total = offs[NEXP];
        if (m0 >= total) return;
        int e = 0;
        while (offs[e + 1] <= m0) e++;
        Bt = BtBase + (size_t)e * N * K;
        bias = biasBase + (size_t)e * N;
    }

    __shared__ ushort_t As[128 * 64];
    __shared__ ushort_t Bs[128 * 64];

    int tid = threadIdx.x;
    int lane = tid & 63, wid = tid >> 6;
    int wm = wid >> 1, wn = wid & 1;
    int q = lane >> 4, lr = lane & 15;

    // staging: chunk L = it*256 + tid ; row = L>>3, stored chunk = L&7,
    // source chunk = stored ^ (row&7)
    size_t Aoff[4], Boff[4];
    int ldsOff[4];
#pragma unroll
    for (int it = 0; it < 4; ++it) {
        int row = it * 32 + (tid >> 3);
        int c = (tid & 7) ^ (row & 7);
        Aoff[it] = (size_t)(m0 + row) * K + c * 8;
        Boff[it] = (size_t)(n0 + row) * K + c * 8;
        ldsOff[it] = (it * 256 + wid * 64) * 8;   // ushort elements
    }

    int rowA[4], rowB[4];
#pragma unroll
    for (int i = 0; i < 4; ++i) {
        rowA[i] = wm * 64 + i * 16 + lr;
        rowB[i] = wn * 64 + i * 16 + lr;
    }

    f32x4 acc[4][4];
#pragma unroll
    for (int i = 0; i < 4; ++i)
#pragma unroll
        for (int j = 0; j < 4; ++j) acc[i][j] = (f32x4)(0.f);

    for (int kb = 0; kb < K; kb += 64) {
#pragma unroll
        for (int it = 0; it < 4; ++it) {
            __builtin_amdgcn_global_load_lds(
                (const __attribute__((address_space(1))) void*)(A + Aoff[it] + kb),
                (__attribute__((address_space(3))) void*)(As + ldsOff[it]), 16, 0, 0);
            __builtin_amdgcn_global_load_lds(
                (const __attribute__((address_space(1))) void*)(Bt + Boff[it] + kb),
                (__attribute__((address_space(3))) void*)(Bs + ldsOff[it]), 16, 0, 0);
        }
        __syncthreads();
#pragma unroll
        for (int ks = 0; ks < 2; ++ks) {
            bf16x8 af[4], bfr[4];
#pragma unroll
            for (int i = 0; i < 4; ++i) {
                int cA = (ks * 4 + q) ^ (rowA[i] & 7);
                af[i] = *(const bf16x8*)(As + rowA[i] * 64 + cA * 8);
                int cB = (ks * 4 + q) ^ (rowB[i] & 7);
                bfr[i] = *(const bf16x8*)(Bs + rowB[i] * 64 + cB * 8);
            }
#pragma unroll
            for (int i = 0; i < 4; ++i)
#pragma unroll
                for (int j = 0; j < 4; ++j)
                    acc[i][j] = __builtin_amdgcn_mfma_f32_16x16x32_bf16(
                        af[i], bfr[j], acc[i][j], 0, 0, 0);
        }
        __syncthreads();
    }

    // epilogue: C/D map col=lane&15, row=(lane>>4)*4+reg
    int colb = n0 + wn * 64 + lr;
    int rowb = m0 + wm * 64 + q * 4;
#pragma unroll
    for (int j = 0; j < 4; ++j) {
        int col = colb + j * 16;
        float bz = bias[col];
#pragma unroll
        for (int i = 0; i < 4; ++i) {
            int row = rowb + i * 16;
#pragma unroll
            for (int r = 0; r < 4; ++r) {
                float v = acc[i][j][r] + bz;
                if (ACT_GELU) v = gelu_exact(v);
                if (OUT_BF16)
                    ((ushort_t*)Cout)[(size_t)(row + r) * N + col] = f2b(v);
                else
                    ((float*)Cout)[(size_t)(row + r) * N + col] = v;
            }
        }
    }
}

// ------------------------------- combine -----------------------------------
__global__ void combine_kernel(float* __restrict__ out, const ushort_t* __restrict__ OutS,
                               const int* __restrict__ slot_of, const float* __restrict__ tw) {
    int t = blockIdx.x;
    int d = threadIdx.x * 4;
    int s0 = slot_of[2 * t], s1 = slot_of[2 * t + 1];
    float w0 = tw[2 * t], w1 = tw[2 * t + 1];
    float* po = out + (size_t)t * DDIM + d;
    float4 o = *(float4*)po;
    const ushort_t* p0 = OutS + (size_t)s0 * DDIM + d;
    const ushort_t* p1 = OutS + (size_t)s1 * DDIM + d;
    o.x += w0 * b2f(p0[0]) + w1 * b2f(p1[0]);
    o.y += w0 * b2f(p0[1]) + w1 * b2f(p1[1]);
    o.z += w0 * b2f(p0[2]) + w1 * b2f(p1[2]);
    o.w += w0 * b2f(p0[3]) + w1 * b2f(p1[3]);
    *(float4*)po = o;
}

// ------------------------------- launch ------------------------------------
extern "C" void kernel_launch(void* const* d_in, const int* in_sizes, int n_in,
                              void* d_out, int out_size, void* d_ws, size_t ws_size,
                              hipStream_t stream) {
    const float* x      = (const float*)d_in[0];
    const float* gw     = (const float*)d_in[1];
    const float* w_in   = (const float*)d_in[2];
    const float* b_in   = (const float*)d_in[3];
    const float* w_out  = (const float*)d_in[4];
    const float* b_out  = (const float*)d_in[5];
    const float* sw_in  = (const float*)d_in[6];
    const float* sb_in  = (const float*)d_in[7];
    const float* sw_out = (const float*)d_in[8];
    const float* sb_out = (const float*)d_in[9];
    float* out = (float*)d_out;

    char* ws = (char*)d_ws;
    int*      tidx    = (int*)(ws + OFF_TIDX);
    float*    tw      = (float*)(ws + OFF_TW);
    int*      offs    = (int*)(ws + OFF_OFFS);
    int*      slot_of = (int*)(ws + OFF_SLOT);
    int*      tok_of  = (int*)(ws + OFF_TOK);
    ushort_t* Xg      = (ushort_t*)(ws + OFF_XG);
    ushort_t* Xb      = (ushort_t*)(ws + OFF_XB);
    ushort_t* Wt      = (ushort_t*)(ws + OFF_W);    // W1t, then W2t, then SW1t
    ushort_t* SW2t    = (ushort_t*)(ws + OFF_SW2);
    ushort_t* Hbuf    = (ushort_t*)(ws + OFF_H);    // Hexp, then Hsh
    ushort_t* OutS    = (ushort_t*)(ws + OFF_OUTS);

    // 1. gate
    gate_kernel<<<T_TOK, 64, 0, stream>>>(x, gw, tidx, tw);
    // 2. scan
    scan_kernel<<<1, 64, 0, stream>>>(tidx, offs, slot_of, tok_of);
    // 3. build bf16 X (gathered + plain)
    build_x<<<SLOT_MAX + T_TOK, 256, 0, stream>>>(x, tok_of, offs, Xg, Xb);
    // 4. W1t = transpose(w_in[e]) : [1024][4096] -> [4096][1024] bf16
    transpose_cvt<<<dim3(DDIM / 64, HDIM / 64, NEXP), 256, 0, stream>>>(w_in, Wt, DDIM, HDIM);
    // 5. Hexp = gelu(Xg @ W1 + b_in)
    gemm_bt<true, true, true><<<dim3(SLOT_MAX / 128, HDIM / 128), 256, 0, stream>>>(
        Xg, Wt, b_in, Hbuf, offs, HDIM, DDIM);
    // 6. W2t = transpose(w_out[e]) : [4096][1024] -> [1024][4096] bf16 (reuse region)
    transpose_cvt<<<dim3(HDIM / 64, DDIM / 64, NEXP), 256, 0, stream>>>(w_out, Wt, HDIM, DDIM);
    // 7. OutS = Hexp @ W2 + b_out
    gemm_bt<true, false, true><<<dim3(SLOT_MAX / 128, DDIM / 128), 256, 0, stream>>>(
        Hbuf, Wt, b_out, OutS, offs, DDIM, HDIM);
    // 8. shared-expert weight transposes (into freed W region)
    transpose_cvt<<<dim3(DDIM / 64, HDIM / 64, 1), 256, 0, stream>>>(sw_in, Wt, DDIM, HDIM);
    transpose_cvt<<<dim3(HDIM / 64, DDIM / 64, 1), 256, 0, stream>>>(sw_out, SW2t, HDIM, DDIM);
    // 9. Hsh = gelu(Xb @ sw_in + sb_in)  (reuse H region)
    gemm_bt<false, true, true><<<dim3(T_TOK / 128, HDIM / 128), 256, 0, stream>>>(
        Xb, Wt, sb_in, Hbuf, nullptr, HDIM, DDIM);
    // 10. out = Hsh @ sw_out + sb_out   (fp32, straight to d_out)
    gemm_bt<false, false, false><<<dim3(T_TOK / 128, DDIM / 128), 256, 0, stream>>>(
        Hbuf, SW2t, sb_out, out, nullptr, DDIM, HDIM);
    // 11. out += w0*OutS[slot0] + w1*OutS[slot1]
    combine_kernel<<<T_TOK, 256, 0, stream>>>(out, OutS, slot_of, tw);
    (void)in_sizes; (void)n_in; (void)out_size; (void)ws_size;
}

// Round 2
// 635.980 us; speedup vs baseline: 1.0798x; 1.0798x over previous
//
#include <hip/hip_runtime.h>
#include <hip/hip_bf16.h>
#include <math.h>

// ---------------------------------------------------------------------------
// MoE block: y = sum_topk2 w_e * FFN_e(x)  +  FFN_shared(x)
// T=4096, D=1024, H=4096, E=8, K=2.  bf16 MFMA compute.
// R2: merged 9-expert GEMMs (shared = expert 8), 2-phase double-buffered
// prefetch GEMM (T3 minimum recipe), parallel atomic routing.
// ---------------------------------------------------------------------------

typedef unsigned short ushort_t;
typedef __attribute__((ext_vector_type(8))) __bf16 bf16x8;
typedef __attribute__((ext_vector_type(4))) float f32x4;

#define T_TOK 4096
#define DDIM  1024
#define HDIM  4096
#define NEXP  8
#define SLOT_MAX 9216            // padded expert rows region
#define M_ALL (SLOT_MAX + T_TOK) // 13312 rows: experts then shared

// workspace layout (bytes)
#define OFF_CNT   0u             // int[8] cnt + int[8] cur
#define OFF_OFFS  64u            // int[16]
#define OFF_TIDX  256u           // int[8192]
#define OFF_TW    33024u         // float[8192]
#define OFF_SLOT  65792u         // int[8192]
#define OFF_TOK   98560u         // int[9216]
#define OFF_XALL  1048576u                        // bf16 [13312][1024] = 27,262,976
#define OFF_OUTS  OFF_XALL                        // bf16 [9216][1024] (aliases Xall, used after GEMM1)
#define OFF_WT    (OFF_XALL + 28311552u)          // bf16 [9][N][K] = 75,497,472
#define OFF_H     (OFF_WT + 75497472u)            // bf16 [13312][4096] = 109,051,904

__device__ __forceinline__ ushort_t f2b(float f) {
    __hip_bfloat16 h = __float2bfloat16(f);
    return *reinterpret_cast<ushort_t*>(&h);
}
__device__ __forceinline__ float b2f(ushort_t u) {
    __hip_bfloat16 h;
    *reinterpret_cast<ushort_t*>(&h) = u;
    return __bfloat162float(h);
}
__device__ __forceinline__ float gelu_exact(float v) {
    return 0.5f * v * (1.0f + erff(v * 0.70710678118654752f));
}

// -------------------------------- init -------------------------------------
__global__ void init_kernel(int* __restrict__ cnt, int* __restrict__ tok_of) {
    int i = blockIdx.x * 256 + threadIdx.x;
    if (i < 16) cnt[i] = 0;
    if (i < SLOT_MAX) tok_of[i] = -1;
}

// -------------------------------- gate -------------------------------------
__global__ void gate_kernel(const float* __restrict__ x, const float* __restrict__ gw,
                            int* __restrict__ tidx, float* __restrict__ tw,
                            int* __restrict__ cnt) {
    int t = blockIdx.x;
    int l = threadIdx.x;
    float acc[NEXP];
#pragma unroll
    for (int e = 0; e < NEXP; ++e) acc[e] = 0.f;
    for (int i = 0; i < DDIM / 64; ++i) {
        float xi = x[(size_t)t * DDIM + i * 64 + l];
#pragma unroll
        for (int e = 0; e < NEXP; ++e)
            acc[e] += xi * gw[e * DDIM + i * 64 + l];
    }
#pragma unroll
    for (int e = 0; e < NEXP; ++e)
        for (int off = 32; off; off >>= 1) acc[e] += __shfl_xor(acc[e], off);
    if (l == 0) {
        float m = acc[0];
#pragma unroll
        for (int e = 1; e < NEXP; ++e) m = fmaxf(m, acc[e]);
        float ex[NEXP], Z = 0.f;
#pragma unroll
        for (int e = 0; e < NEXP; ++e) { ex[e] = __expf(acc[e] - m); Z += ex[e]; }
        int b0 = 0;
#pragma unroll
        for (int e = 1; e < NEXP; ++e) if (ex[e] > ex[b0]) b0 = e;
        int b1 = (b0 == 0) ? 1 : 0;
#pragma unroll
        for (int e = 0; e < NEXP; ++e) if (e != b0 && ex[e] > ex[b1]) b1 = e;
        float inv = 1.0f / Z;
        tidx[2 * t] = b0; tidx[2 * t + 1] = b1;
        tw[2 * t] = ex[b0] * inv; tw[2 * t + 1] = ex[b1] * inv;
        atomicAdd(&cnt[b0], 1);
        atomicAdd(&cnt[b1], 1);
    }
}

// ------------------------------ offsets ------------------------------------
__global__ void offs_kernel(const int* __restrict__ cnt, int* __restrict__ offs) {
    if (threadIdx.x == 0 && blockIdx.x == 0) {
        int o = 0;
#pragma unroll
        for (int e = 0; e < NEXP; ++e) {
            offs[e] = o;
            o += (cnt[e] + 127) & ~127;
        }
        offs[NEXP] = o;
    }
}

// ------------------------------- assign ------------------------------------
// slot order within an expert is atomic-race-dependent, but the OUTPUT is
// permutation-invariant (each slot row computed independently), so results
// are identical across runs.
__global__ void assign_kernel(const int* __restrict__ tidx, const int* __restrict__ offs,
                              int* __restrict__ cur, int* __restrict__ slot_of,
                              int* __restrict__ tok_of) {
    int i = blockIdx.x * 256 + threadIdx.x;
    if (i >= 2 * T_TOK) return;
    int e = tidx[i];
    int s = offs[e] + atomicAdd(&cur[e], 1);
    slot_of[i] = s;
    tok_of[s] = i >> 1;
}

// ------------------------------- build X -----------------------------------
__global__ void build_x(const float* __restrict__ x, const int* __restrict__ tok_of,
                        const int* __restrict__ offs, ushort_t* __restrict__ Xall) {
    int b = blockIdx.x;
    int k = threadIdx.x * 4;
    int t;
    if (b < SLOT_MAX) {
        if (b >= offs[NEXP]) return;
        t = tok_of[b];
    } else {
        t = b - SLOT_MAX;
    }
    float4 v = make_float4(0.f, 0.f, 0.f, 0.f);
    if (t >= 0) v = *(const float4*)(x + (size_t)t * DDIM + k);
    ushort_t* p = Xall + (size_t)b * DDIM + k;
    p[0] = f2b(v.x); p[1] = f2b(v.y); p[2] = f2b(v.z); p[3] = f2b(v.w);
}

// --------------------------- transpose + cvt -------------------------------
// in [K][N] fp32 -> out [N][K] bf16 ; grid (K/64, N/64, batch)
__global__ void transpose_cvt(const float* __restrict__ in, ushort_t* __restrict__ out,
                              int K, int N) {
    __shared__ float t[64][65];
    size_t zoff = (size_t)blockIdx.z * K * N;
    in += zoff; out += zoff;
    int k0 = blockIdx.x * 64, n0 = blockIdx.y * 64;
    int c = threadIdx.x & 63, r4 = threadIdx.x >> 6;
#pragma unroll
    for (int i = 0; i < 16; ++i) {
        int r = r4 + i * 4;
        t[r][c] = in[(size_t)(k0 + r) * N + n0 + c];
    }
    __syncthreads();
#pragma unroll
    for (int i = 0; i < 16; ++i) {
        int r = r4 + i * 4;
        out[(size_t)(n0 + r) * K + k0 + c] = f2b(t[c][r]);
    }
}

// ------------------------------ GEMM (bt) ----------------------------------
// C[M,N] = act(A[M,K] @ Bt[e][N,K]^T + bias), rows grouped by expert
// (128-aligned), expert 8 = shared. 128x128 tile, BK=64, 4 waves,
// mfma_f32_16x16x32_bf16, XOR-swizzled LDS, 2-phase double-buffered prefetch:
//   stage(t+1, buf^1); compute(buf); __syncthreads(); toggle
// __syncthreads' vmcnt(0)+lgkmcnt(0) drain lands AFTER compute -> HBM latency
// hidden under MFMA instead of serialized before it.
template <bool ACT_GELU, bool FFN2>
__global__ __launch_bounds__(256) void gemm_moe(
    const ushort_t* __restrict__ A, const ushort_t* __restrict__ WtBase,
    const float* __restrict__ bExp, const float* __restrict__ bSh,
    ushort_t* __restrict__ Cb, float* __restrict__ Cf,
    const int* __restrict__ offs, int N, int K) {
    int m0 = blockIdx.x * 128, n0 = blockIdx.y * 128;
    int e;
    if (m0 >= SLOT_MAX) {
        e = NEXP;                                  // shared region
    } else {
        if (m0 >= offs[NEXP]) return;              // dead pad zone
        e = 0;
        while (offs[e + 1] <= m0) e++;
    }
    const ushort_t* Bt = WtBase + (size_t)e * N * K;
    const float* bias = (e == NEXP) ? bSh : bExp + (size_t)e * N;

    __shared__ ushort_t As[2][128 * 64];
    __shared__ ushort_t Bs[2][128 * 64];

    int tid = threadIdx.x;
    int lane = tid & 63, wid = tid >> 6;
    int wm = wid >> 1, wn = wid & 1;
    int q = lane >> 4, lr = lane & 15;

    // staging: chunk L = it*256 + tid ; row = L>>3, stored chunk = L&7,
    // source chunk = stored ^ (row&7)  (rule #21: pre-swizzled source)
    size_t Aoff[4], Boff[4];
    int ldsOff[4];
#pragma unroll
    for (int it = 0; it < 4; ++it) {
        int row = it * 32 + (tid >> 3);
        int c = (tid & 7) ^ (row & 7);
        Aoff[it] = (size_t)(m0 + row) * K + c * 8;
        Boff[it] = (size_t)(n0 + row) * K + c * 8;
        ldsOff[it] = (it * 256 + wid * 64) * 8;   // ushort elements
    }

    int rowA[4], rowB[4];
#pragma unroll
    for (int i = 0; i < 4; ++i) {
        rowA[i] = wm * 64 + i * 16 + lr;
        rowB[i] = wn * 64 + i * 16 + lr;
    }

    f32x4 acc[4][4];
#pragma unroll
    for (int i = 0; i < 4; ++i)
#pragma unroll
        for (int j = 0; j < 4; ++j) acc[i][j] = (f32x4)(0.f);

    auto stage = [&](int kb, int buf) {
#pragma unroll
        for (int it = 0; it < 4; ++it) {
            __builtin_amdgcn_global_load_lds(
                (const __attribute__((address_space(1))) void*)(A + Aoff[it] + kb),
                (__attribute__((address_space(3))) void*)(&As[buf][ldsOff[it]]), 16, 0, 0);
            __builtin_amdgcn_global_load_lds(
                (const __attribute__((address_space(1))) void*)(Bt + Boff[it] + kb),
                (__attribute__((address_space(3))) void*)(&Bs[buf][ldsOff[it]]), 16, 0, 0);
        }
    };
    auto compute = [&](int buf) {
#pragma unroll
        for (int ks = 0; ks < 2; ++ks) {
            bf16x8 af[4], bfr[4];
#pragma unroll
            for (int i = 0; i < 4; ++i) {
                int cA = (ks * 4 + q) ^ (rowA[i] & 7);
                af[i] = *(const bf16x8*)(&As[buf][rowA[i] * 64 + cA * 8]);
                int cB = (ks * 4 + q) ^ (rowB[i] & 7);
                bfr[i] = *(const bf16x8*)(&Bs[buf][rowB[i] * 64 + cB * 8]);
            }
#pragma unroll
            for (int i = 0; i < 4; ++i)
#pragma unroll
                for (int j = 0; j < 4; ++j)
                    acc[i][j] = __builtin_amdgcn_mfma_f32_16x16x32_bf16(
                        af[i], bfr[j], acc[i][j], 0, 0, 0);
        }
    };

    const int nk = K >> 6;
    stage(0, 0);
    __syncthreads();
    int cur = 0;
    for (int t = 0; t < nk; ++t) {
        if (t + 1 < nk) stage((t + 1) << 6, cur ^ 1);
        compute(cur);
        __syncthreads();
        cur ^= 1;
    }

    // epilogue: C/D map col=lane&15, row=(lane>>4)*4+reg
    int colb = n0 + wn * 64 + lr;
    int rowb = m0 + wm * 64 + q * 4;
#pragma unroll
    for (int j = 0; j < 4; ++j) {
        int col = colb + j * 16;
        float bz = bias[col];
#pragma unroll
        for (int i = 0; i < 4; ++i) {
            int row = rowb + i * 16;
#pragma unroll
            for (int r = 0; r < 4; ++r) {
                float v = acc[i][j][r] + bz;
                if (ACT_GELU) v = gelu_exact(v);
                if (!FFN2 || e < NEXP)
                    Cb[(size_t)(row + r) * N + col] = f2b(v);
                else
                    Cf[(size_t)(row + r - SLOT_MAX) * N + col] = v;
            }
        }
    }
}

// ------------------------------- combine -----------------------------------
__global__ void combine_kernel(float* __restrict__ out, const ushort_t* __restrict__ OutS,
                               const int* __restrict__ slot_of, const float* __restrict__ tw) {
    int t = blockIdx.x;
    int d = threadIdx.x * 4;
    int s0 = slot_of[2 * t], s1 = slot_of[2 * t + 1];
    float w0 = tw[2 * t], w1 = tw[2 * t + 1];
    float* po = out + (size_t)t * DDIM + d;
    float4 o = *(float4*)po;
    const ushort_t* p0 = OutS + (size_t)s0 * DDIM + d;
    const ushort_t* p1 = OutS + (size_t)s1 * DDIM + d;
    o.x += w0 * b2f(p0[0]) + w1 * b2f(p1[0]);
    o.y += w0 * b2f(p0[1]) + w1 * b2f(p1[1]);
    o.z += w0 * b2f(p0[2]) + w1 * b2f(p1[2]);
    o.w += w0 * b2f(p0[3]) + w1 * b2f(p1[3]);
    *(float4*)po = o;
}

// ------------------------------- launch ------------------------------------
extern "C" void kernel_launch(void* const* d_in, const int* in_sizes, int n_in,
                              void* d_out, int out_size, void* d_ws, size_t ws_size,
                              hipStream_t stream) {
    const float* x      = (const float*)d_in[0];
    const float* gw     = (const float*)d_in[1];
    const float* w_in   = (const float*)d_in[2];
    const float* b_in   = (const float*)d_in[3];
    const float* w_out  = (const float*)d_in[4];
    const float* b_out  = (const float*)d_in[5];
    const float* sw_in  = (const float*)d_in[6];
    const float* sb_in  = (const float*)d_in[7];
    const float* sw_out = (const float*)d_in[8];
    const float* sb_out = (const float*)d_in[9];
    float* out = (float*)d_out;

    char* ws = (char*)d_ws;
    int*      cnt     = (int*)(ws + OFF_CNT);      // [0..7]=cnt, [8..15]=cur
    int*      offs    = (int*)(ws + OFF_OFFS);
    int*      tidx    = (int*)(ws + OFF_TIDX);
    float*    tw      = (float*)(ws + OFF_TW);
    int*      slot_of = (int*)(ws + OFF_SLOT);
    int*      tok_of  = (int*)(ws + OFF_TOK);
    ushort_t* Xall    = (ushort_t*)(ws + OFF_XALL);
    ushort_t* OutS    = (ushort_t*)(ws + OFF_OUTS); // aliases Xall (used after GEMM1)
    ushort_t* Wt      = (ushort_t*)(ws + OFF_WT);   // [9][N][K], FFN1 then FFN2
    ushort_t* Hbuf    = (ushort_t*)(ws + OFF_H);    // bf16 [13312][4096]

    // routing
    init_kernel<<<(SLOT_MAX + 255) / 256, 256, 0, stream>>>(cnt, tok_of);
    gate_kernel<<<T_TOK, 64, 0, stream>>>(x, gw, tidx, tw, cnt);
    offs_kernel<<<1, 64, 0, stream>>>(cnt, offs);
    assign_kernel<<<(2 * T_TOK + 255) / 256, 256, 0, stream>>>(tidx, offs, cnt + 8,
                                                               slot_of, tok_of);
    build_x<<<M_ALL, 256, 0, stream>>>(x, tok_of, offs, Xall);

    // FFN1 weights: [9][4096][1024] bf16  (w_in experts + sw_in as expert 8)
    transpose_cvt<<<dim3(DDIM / 64, HDIM / 64, NEXP), 256, 0, stream>>>(w_in, Wt, DDIM, HDIM);
    transpose_cvt<<<dim3(DDIM / 64, HDIM / 64, 1), 256, 0, stream>>>(
        sw_in, Wt + (size_t)NEXP * HDIM * DDIM, DDIM, HDIM);
    // H = gelu(Xall @ W1 + b1)
    gemm_moe<true, false><<<dim3(M_ALL / 128, HDIM / 128), 256, 0, stream>>>(
        Xall, Wt, b_in, sb_in, Hbuf, nullptr, offs, HDIM, DDIM);

    // FFN2 weights: [9][1024][4096] bf16
    transpose_cvt<<<dim3(HDIM / 64, DDIM / 64, NEXP), 256, 0, stream>>>(w_out, Wt, HDIM, DDIM);
    transpose_cvt<<<dim3(HDIM / 64, DDIM / 64, 1), 256, 0, stream>>>(
        sw_out, Wt + (size_t)NEXP * HDIM * DDIM, HDIM, DDIM);
    // expert rows -> OutS (bf16); shared rows -> out (fp32, includes bias)
    gemm_moe<false, true><<<dim3(M_ALL / 128, DDIM / 128), 256, 0, stream>>>(
        Hbuf, Wt, b_out, sb_out, OutS, out, offs, DDIM, HDIM);

    // out += w0*OutS[slot0] + w1*OutS[slot1]
    combine_kernel<<<T_TOK, 256, 0, stream>>>(out, OutS, slot_of, tw);
    (void)in_sizes; (void)n_in; (void)out_size; (void)ws_size;
}